// Round 1
// baseline (269.362 us; speedup 1.0000x reference)
//
#include <hip/hip_runtime.h>
#include <stdint.h>

typedef int v4i __attribute__((ext_vector_type(4)));

// Problem dims
#define N_IMG 32
#define C_IN 256
#define H_IN 56
#define W_IN 56
#define C_OUT 256
#define H_OUT 28
#define W_OUT 28
#define H_PAD 58
#define W_PAD 58
#define SP_TOT (N_IMG*H_OUT*W_OUT)   // 25088

#define XPAD_BYTES ((size_t)N_IMG*H_PAD*W_PAD*C_IN)   // 27,557,888
#define WQ_BYTES   ((size_t)9*C_OUT*C_IN)             // 589,824

// ---------------------------------------------------------------------------
// Kernel 1: quantize fp32 NCHW -> int8 NHWC with 1-pixel zero padding.
// One block per (n, h): LDS transpose [w][c] with stride 260 (conflict-free
// both phases). Reads coalesced along w (float4), writes coalesced along c.
// ---------------------------------------------------------------------------
__global__ __launch_bounds__(256) void quant_kernel(const float* __restrict__ x,
                                                    int8_t* __restrict__ xpad) {
    __shared__ int8_t lds[W_IN * 260];
    const int n = blockIdx.x, h = blockIdx.y;
    const int t = threadIdx.x;
    const float* xp = x + (size_t)n * C_IN * H_IN * W_IN + (size_t)h * W_IN;

    // Phase A: read x[n][c][h][w] (float4 along w), quantize, stash to LDS[w][c]
    #pragma unroll
    for (int it = 0; it < 14; ++it) {           // 14*256 = 3584 = 256c * 14 w4
        int idx = it * 256 + t;
        int c = idx / 14, w4 = idx % 14;
        const float4 v = *(const float4*)(xp + (size_t)c * H_IN * W_IN + w4 * 4);
        float f[4] = {v.x, v.y, v.z, v.w};
        #pragma unroll
        for (int i = 0; i < 4; ++i) {
            float qv = rintf(f[i] / 0.05f);     // round-half-even, IEEE div
            qv = fminf(fmaxf(qv, -128.0f), 127.0f);
            lds[(w4 * 4 + i) * 260 + c] = (int8_t)(int)qv;
        }
    }
    __syncthreads();

    // Phase B: write x_pad[n][h+1][w+1][c] with c fastest (coalesced u32)
    int8_t* op = xpad + ((size_t)(n * H_PAD + h + 1) * W_PAD + 1) * C_IN;
    #pragma unroll
    for (int it = 0; it < 14; ++it) {           // 56 w * 64 c4 = 3584
        int idx = it * 256 + t;
        int w = idx >> 6, c4 = idx & 63;
        uint32_t val = *(const uint32_t*)(lds + w * 260 + c4 * 4);
        *(uint32_t*)(op + (size_t)w * C_IN + c4 * 4) = val;
    }
}

// ---------------------------------------------------------------------------
// Kernel 2: repack weights fp32 [co][ci][kh][kw] -> int8 wq[khw][co][ci]
// ---------------------------------------------------------------------------
__global__ __launch_bounds__(256) void wq_kernel(const float* __restrict__ w,
                                                 int8_t* __restrict__ wq) {
    int idx = blockIdx.x * 256 + threadIdx.x;   // < 9*256*256 = 589824
    int ci  = idx & 255;
    int co  = (idx >> 8) & 255;
    int khw = idx >> 16;
    float v = w[(size_t)(co * C_IN + ci) * 9 + khw];
    wq[idx] = (int8_t)(int)rintf(v);
}

// ---------------------------------------------------------------------------
// Kernel 3: implicit-GEMM conv via mfma_i32_16x16x64_i8.
// GEMM: C[co][sp] = sum_k W[co][k] * Im2col[k][sp], k = (tap, ci).
// Wave tile: 64co x 32sp (4 A-frags x 2 B-frags, 8 accumulators).
// Block: 256 thr = 4 waves -> 128co x 64sp. Grid (392, 2).
// A-frag: lane holds W[co = tile + (lane&15)][k = kbase + (lane>>4)*16 .. +16]
// B-frag: lane holds Act[sp = tile + (lane&15)][same k range]  (16B dwordx4)
// C/D: col(sp) = lane&15, row(co) = (lane>>4)*4 + reg   [verified mapping]
// ---------------------------------------------------------------------------
__global__ __launch_bounds__(256) void conv_kernel(const int8_t* __restrict__ xpad,
                                                   const int8_t* __restrict__ wq,
                                                   float* __restrict__ out) {
    const int t = threadIdx.x;
    const int wave = t >> 6, lane = t & 63;
    const int q = lane >> 4, s = lane & 15;
    const int co_base = blockIdx.y * 128 + (wave >> 1) * 64;
    const int sp_base = blockIdx.x * 64 + (wave & 1) * 32;

    size_t wrow[4];
    #pragma unroll
    for (int i = 0; i < 4; ++i)
        wrow[i] = (size_t)(co_base + i * 16 + s) * C_IN + q * 16;

    size_t act_base[2];
    int out_base[2];
    #pragma unroll
    for (int j = 0; j < 2; ++j) {
        int sp = sp_base + j * 16 + s;
        int n  = sp / (H_OUT * W_OUT);
        int r  = sp - n * (H_OUT * W_OUT);
        int ho = r / W_OUT;
        int wo = r - ho * W_OUT;
        act_base[j] = ((size_t)(n * H_PAD + ho * 2) * W_PAD + wo * 2) * C_IN + q * 16;
        out_base[j] = n * (C_OUT * H_OUT * W_OUT) + ho * W_OUT + wo;
    }

    v4i acc[4][2];
    #pragma unroll
    for (int i = 0; i < 4; ++i)
        #pragma unroll
        for (int j = 0; j < 2; ++j)
            acc[i][j] = (v4i){0, 0, 0, 0};

    for (int kh = 0; kh < 3; ++kh) {
        for (int kw = 0; kw < 3; ++kw) {
            const int8_t* wp = wq + (size_t)(kh * 3 + kw) * (C_OUT * C_IN);
            const int8_t* ap = xpad + (size_t)(kh * W_PAD + kw) * C_IN;
            #pragma unroll
            for (int ks = 0; ks < 4; ++ks) {       // 4 x 64 ci = one tap's K
                const int cio = ks * 64;
                v4i a[4], b[2];
                #pragma unroll
                for (int i = 0; i < 4; ++i)
                    a[i] = *(const v4i*)(wp + wrow[i] + cio);
                #pragma unroll
                for (int j = 0; j < 2; ++j)
                    b[j] = *(const v4i*)(ap + act_base[j] + cio);
                #pragma unroll
                for (int i = 0; i < 4; ++i)
                    #pragma unroll
                    for (int j = 0; j < 2; ++j)
                        acc[i][j] = __builtin_amdgcn_mfma_i32_16x16x64_i8(
                            a[i], b[j], acc[i][j], 0, 0, 0);
            }
        }
    }

    #pragma unroll
    for (int j = 0; j < 2; ++j) {
        #pragma unroll
        for (int i = 0; i < 4; ++i) {
            const int co0 = co_base + i * 16 + q * 4;
            #pragma unroll
            for (int r = 0; r < 4; ++r) {
                out[(size_t)out_base[j] + (size_t)(co0 + r) * (H_OUT * W_OUT)] =
                    (float)acc[i][j][r] * 0.0005f;
            }
        }
    }
}

// ---------------------------------------------------------------------------
extern "C" void kernel_launch(void* const* d_in, const int* in_sizes, int n_in,
                              void* d_out, int out_size, void* d_ws, size_t ws_size,
                              hipStream_t stream) {
    const float* x = (const float*)d_in[0];
    const float* w = (const float*)d_in[1];
    float* out = (float*)d_out;
    int8_t* xpad = (int8_t*)d_ws;
    int8_t* wqb  = xpad + XPAD_BYTES;

    // zero the padded activation buffer (ws is poisoned 0xAA before each call)
    hipMemsetAsync(xpad, 0, XPAD_BYTES, stream);
    quant_kernel<<<dim3(N_IMG, H_IN), 256, 0, stream>>>(x, xpad);
    wq_kernel<<<(9 * C_OUT * C_IN) / 256, 256, 0, stream>>>(w, wqb);
    conv_kernel<<<dim3(SP_TOT / 64, 2), 256, 0, stream>>>(xpad, wqb, out);
}

// Round 2
// 191.483 us; speedup vs baseline: 1.4067x; 1.4067x over previous
//
#include <hip/hip_runtime.h>
#include <stdint.h>

typedef int v4i __attribute__((ext_vector_type(4)));

// Problem dims
#define N_IMG 32
#define C_IN 256
#define H_IN 56
#define W_IN 56
#define C_OUT 256
#define H_OUT 28
#define W_OUT 28
#define H_PAD 58
#define W_PAD 58
#define SP_TOT (N_IMG*H_OUT*W_OUT)   // 25088

#define XPAD_BYTES ((size_t)N_IMG*H_PAD*W_PAD*C_IN)   // 27,557,888 (16B aligned)
#define WQ_BYTES   ((size_t)9*C_OUT*C_IN)             // 589,824

__device__ __forceinline__ void glds16(const int8_t* g, int8_t* l) {
    __builtin_amdgcn_global_load_lds(
        (const __attribute__((address_space(1))) void*)g,
        (__attribute__((address_space(3))) void*)l, 16, 0, 0);
}

// ---------------------------------------------------------------------------
// Kernel 1: quantize fp32 NCHW -> int8 NHWC, zero-padding borders inline
// (no separate 27.5MB memset). Grid (N, 58): hp==0/57 rows are zeroed; the
// interior rows transpose via LDS (stride 260 conflict-free) and zero the
// left/right border pixels.
// ---------------------------------------------------------------------------
__global__ __launch_bounds__(256) void quant_kernel(const float* __restrict__ x,
                                                    int8_t* __restrict__ xpad) {
    __shared__ int8_t lds[W_IN * 260];
    const int n = blockIdx.x, hp = blockIdx.y;     // hp in [0,58)
    const int t = threadIdx.x;
    int8_t* row = xpad + ((size_t)n * H_PAD + hp) * W_PAD * C_IN;

    if (hp == 0 || hp == H_PAD - 1) {
        // zero full padded row: 58*256 B = 928 x 16B
        #pragma unroll
        for (int i = 0; i < 4; ++i) {
            int idx = i * 256 + t;
            if (idx < 928) *(int4*)(row + idx * 16) = (int4){0, 0, 0, 0};
        }
        return;
    }
    const int h = hp - 1;
    const float* xp = x + (size_t)n * C_IN * H_IN * W_IN + (size_t)h * W_IN;

    // Phase A: read x[n][c][h][w] (float4 along w), quantize, stash to LDS[w][c]
    #pragma unroll
    for (int it = 0; it < 14; ++it) {           // 14*256 = 3584 = 256c * 14 w4
        int idx = it * 256 + t;
        int c = idx / 14, w4 = idx % 14;
        const float4 v = *(const float4*)(xp + (size_t)c * H_IN * W_IN + w4 * 4);
        float f[4] = {v.x, v.y, v.z, v.w};
        #pragma unroll
        for (int i = 0; i < 4; ++i) {
            float qv = rintf(f[i] / 0.05f);     // round-half-even, IEEE div
            qv = fminf(fmaxf(qv, -128.0f), 127.0f);
            lds[(w4 * 4 + i) * 260 + c] = (int8_t)(int)qv;
        }
    }
    // zero border pixels w_p = 0 and w_p = 57 (32 x 16B), disjoint from Phase B
    if (t < 32) {
        int8_t* p = (t < 16) ? (row + t * 16)
                             : (row + (size_t)(W_PAD - 1) * C_IN + (t - 16) * 16);
        *(int4*)p = (int4){0, 0, 0, 0};
    }
    __syncthreads();

    // Phase B: write x_pad[n][hp][w+1][c], c fastest (coalesced u32)
    int8_t* op = row + C_IN;                    // w_p starts at 1
    #pragma unroll
    for (int it = 0; it < 14; ++it) {           // 56 w * 64 c4 = 3584
        int idx = it * 256 + t;
        int w = idx >> 6, c4 = idx & 63;
        uint32_t val = *(const uint32_t*)(lds + w * 260 + c4 * 4);
        *(uint32_t*)(op + (size_t)w * C_IN + c4 * 4) = val;
    }
}

// ---------------------------------------------------------------------------
// Kernel 2: repack weights fp32 [co][ci][kh][kw] -> int8 wq[khw][co][ci]
// ---------------------------------------------------------------------------
__global__ __launch_bounds__(256) void wq_kernel(const float* __restrict__ w,
                                                 int8_t* __restrict__ wq) {
    int idx = blockIdx.x * 256 + threadIdx.x;   // < 9*256*256 = 589824
    int ci  = idx & 255;
    int co  = (idx >> 8) & 255;
    int khw = idx >> 16;
    float v = w[(size_t)(co * C_IN + ci) * 9 + khw];
    wq[idx] = (int8_t)(int)rintf(v);
}

// ---------------------------------------------------------------------------
// Kernel 3: implicit-GEMM conv, LDS-staged (m97 structure).
// Block 256 thr = 4 waves, tile 128co x 64sp; 9 stages (one 3x3 tap each,
// BK = 256 ci). Per stage: global_load_lds dwordx4 stages W(32KB)+Act(16KB)
// into LDS with XOR chunk swizzle (chunk_stored = chunk ^ (row&15)) ->
// ds_read_b128 fragment reads are bank-conflict-free. 32 MFMA/wave between
// barriers.
// A-frag: W[co = cw + i*16 + s][k-chunk = ks*4 + q]
// B-frag: Act[sp = sw + j*16 + s][same k-chunk]
// C/D: col(sp) = s, row(co) = q*4 + reg   [verified mapping]
// ---------------------------------------------------------------------------
__global__ __launch_bounds__(256) void conv_kernel(const int8_t* __restrict__ xpad,
                                                   const int8_t* __restrict__ wq,
                                                   float* __restrict__ out) {
    __shared__ __align__(16) int8_t lds[49152];  // W: [0,32768) Act: [32768,49152)
    const int t = threadIdx.x;
    const int wave = t >> 6, lane = t & 63;
    const int q = lane >> 4, s = lane & 15;
    const int co_blk = blockIdx.y * 128;
    const int sp_blk = blockIdx.x * 64;

    // ---- staging decode (fixed per thread) ----
    // rows are 256B = 16 chunks of 16B; o = r*4096 + wave*1024 + lane*16
    // row_l = r*16 + wave*4 + q ; chunk_st = lane&15 ; chunk = chunk_st ^ (row_l&15)
    const int row_l4 = wave * 4 + q;                 // row_l mod 16
    const int chunk  = (lane & 15) ^ row_l4;
    const int8_t* gw = wq + (size_t)(co_blk + row_l4) * 256 + chunk * 16; // + r*4096 + tap*65536

    const int8_t* ga[4];
    #pragma unroll
    for (int r = 0; r < 4; ++r) {
        int sp = sp_blk + r * 16 + row_l4;
        int n  = sp / (H_OUT * W_OUT);
        int rm = sp - n * (H_OUT * W_OUT);
        int ho = rm / W_OUT;
        int wo = rm - ho * W_OUT;
        ga[r] = xpad + ((size_t)(n * H_PAD + ho * 2) * W_PAD + wo * 2) * C_IN + chunk * 16;
    }

    int8_t* lw = lds + wave * 1024;           // + r*4096
    int8_t* la = lds + 32768 + wave * 1024;   // + r*4096

    // ---- output mapping ----
    const int cw = (wave >> 1) * 64;          // LDS-local co base of this wave
    const int sw = (wave & 1) * 32;           // LDS-local sp base of this wave
    int out_base[2];
    #pragma unroll
    for (int j = 0; j < 2; ++j) {
        int sp = sp_blk + sw + j * 16 + s;
        int n  = sp / (H_OUT * W_OUT);
        int rm = sp - n * (H_OUT * W_OUT);
        int ho = rm / W_OUT;
        int wo = rm - ho * W_OUT;
        out_base[j] = n * (C_OUT * H_OUT * W_OUT) + ho * W_OUT + wo;
    }

    v4i acc[4][2];
    #pragma unroll
    for (int i = 0; i < 4; ++i)
        #pragma unroll
        for (int j = 0; j < 2; ++j)
            acc[i][j] = (v4i){0, 0, 0, 0};

    // ---- K loop: 9 stages (one tap each) ----
    for (int kh = 0; kh < 3; ++kh) {
        for (int kwv = 0; kwv < 3; ++kwv) {
            __syncthreads();                       // all waves done reading prev stage
            const int woff = (kh * 3 + kwv) * (C_OUT * C_IN);
            const int aoff = (kh * W_PAD + kwv) * C_IN;
            #pragma unroll
            for (int r = 0; r < 8; ++r)
                glds16(gw + woff + r * 4096, lw + r * 4096);
            #pragma unroll
            for (int r = 0; r < 4; ++r)
                glds16(ga[r] + aoff, la + r * 4096);
            __syncthreads();                       // vmcnt(0) drain: LDS ready

            #pragma unroll
            for (int ks = 0; ks < 4; ++ks) {
                const int st = ((ks * 4 + q) ^ s) * 16;   // swizzled chunk offset
                v4i a[4], b[2];
                #pragma unroll
                for (int i = 0; i < 4; ++i)
                    a[i] = *(const v4i*)(lds + (cw + i * 16 + s) * 256 + st);
                #pragma unroll
                for (int j = 0; j < 2; ++j)
                    b[j] = *(const v4i*)(lds + 32768 + (sw + j * 16 + s) * 256 + st);
                #pragma unroll
                for (int i = 0; i < 4; ++i)
                    #pragma unroll
                    for (int j = 0; j < 2; ++j)
                        acc[i][j] = __builtin_amdgcn_mfma_i32_16x16x64_i8(
                            a[i], b[j], acc[i][j], 0, 0, 0);
            }
        }
    }

    // ---- epilogue ----
    #pragma unroll
    for (int j = 0; j < 2; ++j) {
        #pragma unroll
        for (int i = 0; i < 4; ++i) {
            const int co0 = co_blk + cw + i * 16 + q * 4;
            #pragma unroll
            for (int r = 0; r < 4; ++r) {
                out[(size_t)out_base[j] + (size_t)(co0 + r) * (H_OUT * W_OUT)] =
                    (float)acc[i][j][r] * 0.0005f;
            }
        }
    }
}

// ---------------------------------------------------------------------------
extern "C" void kernel_launch(void* const* d_in, const int* in_sizes, int n_in,
                              void* d_out, int out_size, void* d_ws, size_t ws_size,
                              hipStream_t stream) {
    const float* x = (const float*)d_in[0];
    const float* w = (const float*)d_in[1];
    float* out = (float*)d_out;
    int8_t* xpad = (int8_t*)d_ws;
    int8_t* wqb  = xpad + XPAD_BYTES;

    quant_kernel<<<dim3(N_IMG, H_PAD), 256, 0, stream>>>(x, xpad);
    wq_kernel<<<(9 * C_OUT * C_IN) / 256, 256, 0, stream>>>(w, wqb);
    conv_kernel<<<dim3(SP_TOT / 64, 2), 256, 0, stream>>>(xpad, wqb, out);
}